// Round 1
// baseline (698.964 us; speedup 1.0000x reference)
//
#include <hip/hip_runtime.h>
#include <hip/hip_bf16.h>

typedef __bf16 bf16x8 __attribute__((ext_vector_type(8)));
typedef float f32x4 __attribute__((ext_vector_type(4)));

#define G_DIM 128

// ---- helpers ----
__device__ __forceinline__ float bf2f(ushort u) {
  unsigned int x = ((unsigned int)u) << 16;
  return __uint_as_float(x);
}

__device__ __forceinline__ bf16x8 cvt8(float4 f0, float4 f1) {
  bf16x8 v;
  v[0] = (__bf16)f0.x; v[1] = (__bf16)f0.y; v[2] = (__bf16)f0.z; v[3] = (__bf16)f0.w;
  v[4] = (__bf16)f1.x; v[5] = (__bf16)f1.y; v[6] = (__bf16)f1.z; v[7] = (__bf16)f1.w;
  return v;
}

// swizzled ushort index into a row-major [rows][128] bf16 LDS tile.
// kc = 16B chunk index within row (0..15). XOR spreads rows across bank groups.
__device__ __forceinline__ int swz_idx(int row, int kc) {
  return (row * 128 + kc * 8) ^ ((row & 7) << 3);
}

// ---- segment ranges from sorted batch ----
__global__ void k_seg(const int* __restrict__ batch, int* __restrict__ seg, int n, int g) {
  int i = blockIdx.x * blockDim.x + threadIdx.x;
  if (i >= n) return;
  int b = batch[i];
  int prev = (i == 0) ? -1 : batch[i - 1];
  for (int q = prev + 1; q <= b; ++q) seg[q] = i;
  if (i == n - 1) {
    for (int q = b + 1; q <= g; ++q) seg[q] = n;
  }
}

// ---- pooled init state: out0 = relu(segment_sum(x)) ----
__global__ __launch_bounds__(128) void k_pool(const float* __restrict__ x,
                                              const int* __restrict__ seg,
                                              float* __restrict__ out0) {
  int g = blockIdx.x, d = threadIdx.x;
  int s = seg[g], e = seg[g + 1];
  float acc = 0.f;
  for (int i = s; i < e; ++i) acc += x[(long)i * G_DIM + d];
  out0[(long)g * G_DIM + d] = fmaxf(acc, 0.f);
}

// ---- MFMA GEMM: out[r, c] = bias[c] + sum_k A[r,k] * W[c,k]  (A fp32 in, bf16 compute)
// NCOL in {128, 384}. One 64-row tile per block iteration, grid-stride over tiles.
template <int NCOL, bool OUT_BF16>
__global__ __launch_bounds__(256) void k_gemm(const float* __restrict__ A,
                                              const float* __restrict__ W,
                                              const float* __restrict__ bias,
                                              void* __restrict__ outp,
                                              int rows, int out_stride, int ntiles) {
  __shared__ __align__(16) ushort sB[NCOL * 128];
  __shared__ __align__(16) ushort sA[64 * 128];
  const int tid = threadIdx.x;
  // stage W (NCOL x 128 fp32) -> bf16, swizzled; once per block
  for (int c = tid; c < NCOL * 16; c += 256) {
    int row = c >> 4, kc = c & 15;
    const float4* src = (const float4*)(W + (long)row * 128 + kc * 8);
    float4 f0 = src[0], f1 = src[1];
    *(bf16x8*)(&sB[swz_idx(row, kc)]) = cvt8(f0, f1);
  }
  const int lane = tid & 63;
  const int wv = tid >> 6;
  const int l15 = lane & 15;
  const int kg = lane >> 4;  // 0..3
  __syncthreads();

  for (int tile = blockIdx.x; tile < ntiles; tile += gridDim.x) {
    const long row0 = (long)tile * 64;
    // stage A tile (64 x 128), zero-padded past `rows`
    for (int c = tid; c < 64 * 16; c += 256) {
      int r = c >> 4, kc = c & 15;
      long gr = row0 + r;
      bf16x8 v;
      if (gr < rows) {
        const float4* src = (const float4*)(A + gr * 128 + kc * 8);
        float4 f0 = src[0], f1 = src[1];
        v = cvt8(f0, f1);
      } else {
        #pragma unroll
        for (int q = 0; q < 8; ++q) v[q] = (__bf16)0.f;
      }
      *(bf16x8*)(&sA[swz_idx(r, kc)]) = v;
    }
    __syncthreads();

    f32x4 acc[NCOL / 16];
    #pragma unroll
    for (int nt = 0; nt < NCOL / 16; ++nt) acc[nt] = f32x4{0.f, 0.f, 0.f, 0.f};
    const int mrow = wv * 16 + l15;
    #pragma unroll
    for (int ks = 0; ks < 4; ++ks) {
      bf16x8 af = *(const bf16x8*)(&sA[swz_idx(mrow, ks * 4 + kg)]);
      #pragma unroll
      for (int nt = 0; nt < NCOL / 16; ++nt) {
        bf16x8 bfr = *(const bf16x8*)(&sB[swz_idx(nt * 16 + l15, ks * 4 + kg)]);
        acc[nt] = __builtin_amdgcn_mfma_f32_16x16x32_bf16(af, bfr, acc[nt], 0, 0, 0);
      }
    }
    // epilogue: C layout col = lane&15, row = (lane>>4)*4 + j
    #pragma unroll
    for (int nt = 0; nt < NCOL / 16; ++nt) {
      int col = nt * 16 + l15;
      float bv = bias[col];
      #pragma unroll
      for (int j = 0; j < 4; ++j) {
        long r = row0 + wv * 16 + kg * 4 + j;
        if (r < rows) {
          float v = acc[nt][j] + bv;
          if (OUT_BF16)
            ((__bf16*)outp)[r * out_stride + col] = (__bf16)v;
          else
            ((float*)outp)[r * out_stride + col] = v;
        }
      }
    }
    __syncthreads();
  }
}

// ---- fused GATv2 edge-score + segment softmax + weighted aggregation ----
// wave per graph; lane handles dims (2*lane, 2*lane+1). Two-pass online softmax.
__global__ __launch_bounds__(256) void k_gat(const __bf16* __restrict__ xl,
                                             const float* __restrict__ xr,
                                             const int* __restrict__ seg,
                                             const float* __restrict__ att,
                                             const float* __restrict__ gat_bias,
                                             float* __restrict__ h, int G) {
  int wv = (blockIdx.x << 2) + (threadIdx.x >> 6);
  int lane = threadIdx.x & 63;
  if (wv >= G) return;
  int s = seg[wv], e = seg[wv + 1];
  int d0 = lane * 2;
  float xr0 = xr[(long)wv * G_DIM + d0];
  float xr1 = xr[(long)wv * G_DIM + d0 + 1];
  float a0 = att[d0], a1 = att[d0 + 1];

  float m = -1e30f, den = 0.f;
  for (int i = s; i < e; ++i) {
    ushort2 u = *(const ushort2*)((const ushort*)xl + (long)i * G_DIM + d0);
    float v0 = bf2f(u.x) + xr0;
    float v1 = bf2f(u.y) + xr1;
    v0 = v0 > 0.f ? v0 : 0.01f * v0;
    v1 = v1 > 0.f ? v1 : 0.01f * v1;
    float p = v0 * a0 + v1 * a1;
    #pragma unroll
    for (int off = 32; off; off >>= 1) p += __shfl_xor(p, off, 64);
    float nm = fmaxf(m, p);
    den = den * __expf(m - nm) + __expf(p - nm);
    m = nm;
  }
  float inv = (e > s) ? 1.f / den : 0.f;
  float acc0 = 0.f, acc1 = 0.f;
  for (int i = s; i < e; ++i) {
    ushort2 u = *(const ushort2*)((const ushort*)xl + (long)i * G_DIM + d0);
    float x0 = bf2f(u.x), x1 = bf2f(u.y);
    float v0 = x0 + xr0, v1 = x1 + xr1;
    v0 = v0 > 0.f ? v0 : 0.01f * v0;
    v1 = v1 > 0.f ? v1 : 0.01f * v1;
    float p = v0 * a0 + v1 * a1;
    #pragma unroll
    for (int off = 32; off; off >>= 1) p += __shfl_xor(p, off, 64);
    float al = __expf(p - m) * inv;
    acc0 += al * x0;
    acc1 += al * x1;
  }
  float o0 = acc0 + gat_bias[d0];
  float o1 = acc1 + gat_bias[d0 + 1];
  o0 = o0 > 0.f ? o0 : __expf(o0) - 1.f;  // elu
  o1 = o1 > 0.f ? o1 : __expf(o1) - 1.f;
  h[(long)wv * G_DIM + d0] = o0;
  h[(long)wv * G_DIM + d0 + 1] = o1;
}

// ---- GRU combine + relu ----
__global__ void k_gru(const float* __restrict__ gi, const float* __restrict__ gh,
                      const float* __restrict__ hprev, float* __restrict__ outn, int total) {
  int idx = blockIdx.x * blockDim.x + threadIdx.x;
  if (idx >= total) return;
  int g = idx >> 7, d = idx & 127;
  const float* gir = gi + (long)g * 384;
  const float* ghr = gh + (long)g * 384;
  float ir = gir[d], iz = gir[128 + d], in_ = gir[256 + d];
  float hr = ghr[d], hz = ghr[128 + d], hn = ghr[256 + d];
  float r = 1.f / (1.f + __expf(-(ir + hr)));
  float z = 1.f / (1.f + __expf(-(iz + hz)));
  float n = tanhf(in_ + r * hn);
  float o = hprev[idx];
  float v = (1.f - z) * n + z * o;
  outn[idx] = fmaxf(v, 0.f);
}

extern "C" void kernel_launch(void* const* d_in, const int* in_sizes, int n_in,
                              void* d_out, int out_size, void* d_ws, size_t ws_size,
                              hipStream_t stream) {
  const float* x        = (const float*)d_in[0];
  const int*   batch    = (const int*)d_in[1];
  const float* Wl       = (const float*)d_in[2];
  const float* bl       = (const float*)d_in[3];
  const float* Wr       = (const float*)d_in[4];
  const float* br       = (const float*)d_in[5];
  const float* att      = (const float*)d_in[6];
  const float* gat_bias = (const float*)d_in[7];
  const float* W_ih     = (const float*)d_in[8];
  const float* W_hh     = (const float*)d_in[9];
  const float* b_ih     = (const float*)d_in[10];
  const float* b_hh     = (const float*)d_in[11];
  const float* Wfc      = (const float*)d_in[12];
  const float* bfc      = (const float*)d_in[13];
  const int N = in_sizes[1];
  const int G = out_size / G_DIM;
  float* outf = (float*)d_out;

  char* ws = (char*)d_ws;
  size_t off = 0;
  auto alloc = [&](size_t bytes) -> void* {
    void* p = ws + off;
    off = (off + bytes + 255) & ~(size_t)255;
    return p;
  };
  int*    seg   = (int*)alloc(((size_t)G + 1) * sizeof(int));
  float*  out_a = (float*)alloc((size_t)G * G_DIM * sizeof(float));
  float*  out_b = (float*)alloc((size_t)G * G_DIM * sizeof(float));
  float*  xr    = (float*)alloc((size_t)G * G_DIM * sizeof(float));
  float*  hbuf  = (float*)alloc((size_t)G * G_DIM * sizeof(float));
  float*  gi    = (float*)alloc((size_t)G * 384 * sizeof(float));
  float*  gh    = (float*)alloc((size_t)G * 384 * sizeof(float));
  __bf16* xl    = (__bf16*)alloc((size_t)N * G_DIM * sizeof(ushort));
  (void)ws_size; (void)n_in;

  k_seg<<<(N + 255) / 256, 256, 0, stream>>>(batch, seg, N, G);
  k_pool<<<G, 128, 0, stream>>>(x, seg, out_a);

  const int ntiles_big = (N + 63) / 64;
  k_gemm<128, true><<<2048, 256, 0, stream>>>(x, Wl, bl, (void*)xl, N, G_DIM, ntiles_big);

  const int ntiles_g = (G + 63) / 64;
  const float* cur = out_a;
  float* nxt = out_b;
  for (int t = 0; t < 3; ++t) {
    k_gemm<128, false><<<ntiles_g, 256, 0, stream>>>(cur, Wr, br, (void*)xr, G, G_DIM, ntiles_g);
    k_gat<<<G / 4, 256, 0, stream>>>(xl, xr, seg, att, gat_bias, hbuf, G);
    k_gemm<384, false><<<ntiles_g, 256, 0, stream>>>(hbuf, W_ih, b_ih, (void*)gi, G, 384, ntiles_g);
    k_gemm<384, false><<<ntiles_g, 256, 0, stream>>>(cur, W_hh, b_hh, (void*)gh, G, 384, ntiles_g);
    k_gru<<<(G * G_DIM + 255) / 256, 256, 0, stream>>>(gi, gh, cur, nxt, G * G_DIM);
    const float* tmp = cur;
    cur = nxt;
    nxt = (float*)tmp;
  }
  k_gemm<128, false><<<ntiles_g, 256, 0, stream>>>(cur, Wfc, bfc, (void*)outf, G, G_DIM, ntiles_g);
}

// Round 2
// 500.947 us; speedup vs baseline: 1.3953x; 1.3953x over previous
//
#include <hip/hip_runtime.h>
#include <hip/hip_bf16.h>

typedef __bf16 bf16x8 __attribute__((ext_vector_type(8)));
typedef float f32x4 __attribute__((ext_vector_type(4)));

#define G_DIM 128

// ---- helpers ----
__device__ __forceinline__ float bf2f(ushort u) {
  return __uint_as_float(((unsigned int)u) << 16);
}

__device__ __forceinline__ bf16x8 cvt8(float4 f0, float4 f1) {
  bf16x8 v;
  v[0] = (__bf16)f0.x; v[1] = (__bf16)f0.y; v[2] = (__bf16)f0.z; v[3] = (__bf16)f0.w;
  v[4] = (__bf16)f1.x; v[5] = (__bf16)f1.y; v[6] = (__bf16)f1.z; v[7] = (__bf16)f1.w;
  return v;
}

// swizzled ushort index into a row-major [rows][128] bf16 LDS tile.
// kc = 16B chunk index within row (0..15). XOR spreads rows across bank groups.
__device__ __forceinline__ int swz_idx(int row, int kc) {
  return (row * 128 + kc * 8) ^ ((row & 7) << 3);
}

// ---- segment ranges from sorted batch ----
__global__ void k_seg(const int* __restrict__ batch, int* __restrict__ seg, int n, int g) {
  int i = blockIdx.x * blockDim.x + threadIdx.x;
  if (i >= n) return;
  int b = batch[i];
  int prev = (i == 0) ? -1 : batch[i - 1];
  for (int q = prev + 1; q <= b; ++q) seg[q] = i;
  if (i == n - 1) {
    for (int q = b + 1; q <= g; ++q) seg[q] = n;
  }
}

__global__ void k_zero4(float4* __restrict__ p, int n4) {
  int i = blockIdx.x * blockDim.x + threadIdx.x;
  if (i < n4) p[i] = float4{0.f, 0.f, 0.f, 0.f};
}

__global__ void k_relu4(float4* __restrict__ p, int n4) {
  int i = blockIdx.x * blockDim.x + threadIdx.x;
  if (i < n4) {
    float4 v = p[i];
    v.x = fmaxf(v.x, 0.f); v.y = fmaxf(v.y, 0.f);
    v.z = fmaxf(v.z, 0.f); v.w = fmaxf(v.w, 0.f);
    p[i] = v;
  }
}

// ---- big fused kernel: xl = bf16(x @ Wl.T + bl)  AND  pool += segment partial sums of x ----
__global__ __launch_bounds__(256) void k_xlgemm(const float* __restrict__ x,
                                                const float* __restrict__ W,
                                                const float* __restrict__ bias,
                                                const int* __restrict__ batch,
                                                __bf16* __restrict__ xl,
                                                float* __restrict__ pool,
                                                int rows, int ntiles) {
  __shared__ __align__(16) ushort sB[128 * 128];
  __shared__ __align__(16) ushort sA[64 * 128];
  __shared__ int sBatch[64];
  const int tid = threadIdx.x;
  // stage W (128x128 fp32) -> bf16, swizzled; once per block
  for (int c = tid; c < 128 * 16; c += 256) {
    int row = c >> 4, kc = c & 15;
    const float4* src = (const float4*)(W + (long)row * 128 + kc * 8);
    *(bf16x8*)(&sB[swz_idx(row, kc)]) = cvt8(src[0], src[1]);
  }
  const int lane = tid & 63;
  const int wv = tid >> 6;
  const int l15 = lane & 15;
  const int kg = lane >> 4;
  __syncthreads();

  for (int tile = blockIdx.x; tile < ntiles; tile += gridDim.x) {
    const long row0 = (long)tile * 64;
    if (tid < 64) {
      long gr = row0 + tid;
      sBatch[tid] = (gr < rows) ? batch[gr] : -1;
    }
    for (int c = tid; c < 64 * 16; c += 256) {
      int r = c >> 4, kc = c & 15;
      long gr = row0 + r;
      bf16x8 v;
      if (gr < rows) {
        const float4* src = (const float4*)(x + gr * 128 + kc * 8);
        v = cvt8(src[0], src[1]);
      } else {
        #pragma unroll
        for (int q = 0; q < 8; ++q) v[q] = (__bf16)0.f;
      }
      *(bf16x8*)(&sA[swz_idx(r, kc)]) = v;
    }
    __syncthreads();

    // MFMA: 64x128 tile
    f32x4 acc[8];
    #pragma unroll
    for (int nt = 0; nt < 8; ++nt) acc[nt] = f32x4{0.f, 0.f, 0.f, 0.f};
    const int mrow = wv * 16 + l15;
    #pragma unroll
    for (int ks = 0; ks < 4; ++ks) {
      bf16x8 af = *(const bf16x8*)(&sA[swz_idx(mrow, ks * 4 + kg)]);
      #pragma unroll
      for (int nt = 0; nt < 8; ++nt) {
        bf16x8 bfr = *(const bf16x8*)(&sB[swz_idx(nt * 16 + l15, ks * 4 + kg)]);
        acc[nt] = __builtin_amdgcn_mfma_f32_16x16x32_bf16(af, bfr, acc[nt], 0, 0, 0);
      }
    }
    #pragma unroll
    for (int nt = 0; nt < 8; ++nt) {
      int col = nt * 16 + l15;
      float bv = bias[col];
      #pragma unroll
      for (int j = 0; j < 4; ++j) {
        long r = row0 + wv * 16 + kg * 4 + j;
        if (r < rows) xl[r * 128 + col] = (__bf16)(acc[nt][j] + bv);
      }
    }

    // pool: thread handles one column over 32 rows; segment-boundary atomics
    {
      int col = tid & 127;
      int half = tid >> 7;
      int cur_b = -1;
      float pacc = 0.f;
      int rbeg = half * 32;
      #pragma unroll 1
      for (int r = rbeg; r < rbeg + 32; ++r) {
        int b = sBatch[r];
        if (b != cur_b) {
          if (cur_b >= 0) atomicAdd(&pool[(long)cur_b * 128 + col], pacc);
          pacc = 0.f;
          cur_b = b;
        }
        if (b >= 0) pacc += bf2f(sA[swz_idx(r, col >> 3) + (col & 7)]);
      }
      if (cur_b >= 0) atomicAdd(&pool[(long)cur_b * 128 + col], pacc);
    }
    __syncthreads();
  }
}

// ---- small GEMM: out[r, c] = bias[c] + sum_k A[r,k] * W[c,k], 128 cols, fp32 out ----
__global__ __launch_bounds__(256) void k_gemm128(const float* __restrict__ A,
                                                 const float* __restrict__ W,
                                                 const float* __restrict__ bias,
                                                 float* __restrict__ out,
                                                 int rows) {
  __shared__ __align__(16) ushort sB[128 * 128];
  __shared__ __align__(16) ushort sA[64 * 128];
  const int tid = threadIdx.x;
  const long row0 = (long)blockIdx.x * 64;
  for (int c = tid; c < 128 * 16; c += 256) {
    int row = c >> 4, kc = c & 15;
    const float4* src = (const float4*)(W + (long)row * 128 + kc * 8);
    *(bf16x8*)(&sB[swz_idx(row, kc)]) = cvt8(src[0], src[1]);
  }
  for (int c = tid; c < 64 * 16; c += 256) {
    int r = c >> 4, kc = c & 15;
    long gr = row0 + r;
    bf16x8 v;
    if (gr < rows) {
      const float4* src = (const float4*)(A + gr * 128 + kc * 8);
      v = cvt8(src[0], src[1]);
    } else {
      #pragma unroll
      for (int q = 0; q < 8; ++q) v[q] = (__bf16)0.f;
    }
    *(bf16x8*)(&sA[swz_idx(r, kc)]) = v;
  }
  const int lane = tid & 63;
  const int wv = tid >> 6;
  const int l15 = lane & 15;
  const int kg = lane >> 4;
  __syncthreads();

  f32x4 acc[8];
  #pragma unroll
  for (int nt = 0; nt < 8; ++nt) acc[nt] = f32x4{0.f, 0.f, 0.f, 0.f};
  const int mrow = wv * 16 + l15;
  #pragma unroll
  for (int ks = 0; ks < 4; ++ks) {
    bf16x8 af = *(const bf16x8*)(&sA[swz_idx(mrow, ks * 4 + kg)]);
    #pragma unroll
    for (int nt = 0; nt < 8; ++nt) {
      bf16x8 bfr = *(const bf16x8*)(&sB[swz_idx(nt * 16 + l15, ks * 4 + kg)]);
      acc[nt] = __builtin_amdgcn_mfma_f32_16x16x32_bf16(af, bfr, acc[nt], 0, 0, 0);
    }
  }
  #pragma unroll
  for (int nt = 0; nt < 8; ++nt) {
    int col = nt * 16 + l15;
    float bv = bias[col];
    #pragma unroll
    for (int j = 0; j < 4; ++j) {
      long r = row0 + wv * 16 + kg * 4 + j;
      if (r < rows) out[r * 128 + col] = acc[nt][j] + bv;
    }
  }
}

// ---- fused GATv2: single-pass online softmax + weighted aggregation ----
// wave per graph; lane handles dims (2*lane, 2*lane+1); 2-deep load prefetch.
__global__ __launch_bounds__(256) void k_gat(const __bf16* __restrict__ xl,
                                             const float* __restrict__ xr,
                                             const int* __restrict__ seg,
                                             const float* __restrict__ att,
                                             const float* __restrict__ gat_bias,
                                             float* __restrict__ h, int G) {
  int wv = (blockIdx.x << 2) + (threadIdx.x >> 6);
  int lane = threadIdx.x & 63;
  if (wv >= G) return;
  int s = seg[wv], e = seg[wv + 1];
  int d0 = lane * 2;
  float xr0 = xr[(long)wv * G_DIM + d0];
  float xr1 = xr[(long)wv * G_DIM + d0 + 1];
  float a0 = att[d0], a1 = att[d0 + 1];

  float m = -1e30f, den = 0.f, acc0 = 0.f, acc1 = 0.f;
  ushort2 u = (s < e) ? *(const ushort2*)((const ushort*)xl + (long)s * G_DIM + d0)
                      : ushort2{0, 0};
  for (int i = s; i < e; ++i) {
    ushort2 un = (i + 1 < e)
        ? *(const ushort2*)((const ushort*)xl + (long)(i + 1) * G_DIM + d0)
        : u;
    float x0 = bf2f(u.x), x1 = bf2f(u.y);
    float v0 = x0 + xr0, v1 = x1 + xr1;
    v0 = v0 > 0.f ? v0 : 0.01f * v0;
    v1 = v1 > 0.f ? v1 : 0.01f * v1;
    float p = v0 * a0 + v1 * a1;
    #pragma unroll
    for (int off = 32; off; off >>= 1) p += __shfl_xor(p, off, 64);
    float nm = fmaxf(m, p);
    float sc = __expf(m - nm);
    float w = __expf(p - nm);
    den = den * sc + w;
    acc0 = acc0 * sc + w * x0;
    acc1 = acc1 * sc + w * x1;
    m = nm;
    u = un;
  }
  float inv = (e > s) ? 1.f / den : 0.f;
  float o0 = acc0 * inv + gat_bias[d0];
  float o1 = acc1 * inv + gat_bias[d0 + 1];
  o0 = o0 > 0.f ? o0 : __expf(o0) - 1.f;  // elu
  o1 = o1 > 0.f ? o1 : __expf(o1) - 1.f;
  h[(long)wv * G_DIM + d0] = o0;
  h[(long)wv * G_DIM + d0 + 1] = o1;
}

// ---- fused GRU: gi=h@W_ih.T, gh=cur@W_hh.T, gate math, relu -> nxt. gi/gh never hit HBM.
__global__ __launch_bounds__(256) void k_grublock(const float* __restrict__ h,
                                                  const float* __restrict__ cur,
                                                  const float* __restrict__ W_ih,
                                                  const float* __restrict__ W_hh,
                                                  const float* __restrict__ b_ih,
                                                  const float* __restrict__ b_hh,
                                                  float* __restrict__ nxt, int G) {
  __shared__ __align__(16) ushort sA1[64 * 128];  // h tile
  __shared__ __align__(16) ushort sA2[64 * 128];  // cur tile
  __shared__ __align__(16) ushort sW[128 * 128];  // one gate of one W at a time
  const int tid = threadIdx.x;
  const int lane = tid & 63, wv = tid >> 6, l15 = lane & 15, kg = lane >> 4;
  const long row0 = (long)blockIdx.x * 64;
  const int mrow = wv * 16 + l15;

  for (int c = tid; c < 64 * 16; c += 256) {
    int r = c >> 4, kc = c & 15;
    long gr = row0 + r;
    const float4* s1 = (const float4*)(h + gr * 128 + kc * 8);
    const float4* s2 = (const float4*)(cur + gr * 128 + kc * 8);
    *(bf16x8*)(&sA1[swz_idx(r, kc)]) = cvt8(s1[0], s1[1]);
    *(bf16x8*)(&sA2[swz_idx(r, kc)]) = cvt8(s2[0], s2[1]);
  }

  f32x4 rp[8], zp[8], inn[8], hnn[8];
  #pragma unroll
  for (int nt = 0; nt < 8; ++nt) {
    rp[nt] = f32x4{0.f, 0.f, 0.f, 0.f};
    zp[nt] = f32x4{0.f, 0.f, 0.f, 0.f};
    inn[nt] = f32x4{0.f, 0.f, 0.f, 0.f};
    hnn[nt] = f32x4{0.f, 0.f, 0.f, 0.f};
  }

#define STAGE_W(WSRC, gate)                                                   \
  __syncthreads();                                                            \
  for (int c = tid; c < 128 * 16; c += 256) {                                 \
    int r = c >> 4, kc = c & 15;                                              \
    const float4* src = (const float4*)((WSRC) + ((long)(gate)*128 + r) * 128 + kc * 8); \
    *(bf16x8*)(&sW[swz_idx(r, kc)]) = cvt8(src[0], src[1]);                   \
  }                                                                           \
  __syncthreads();

#define MM(ACC, SAX)                                                          \
  _Pragma("unroll") for (int ks = 0; ks < 4; ++ks) {                          \
    bf16x8 af = *(const bf16x8*)(&SAX[swz_idx(mrow, ks * 4 + kg)]);           \
    _Pragma("unroll") for (int nt = 0; nt < 8; ++nt) {                        \
      bf16x8 bfr = *(const bf16x8*)(&sW[swz_idx(nt * 16 + l15, ks * 4 + kg)]);\
      ACC[nt] = __builtin_amdgcn_mfma_f32_16x16x32_bf16(af, bfr, ACC[nt], 0, 0, 0); \
    }                                                                         \
  }

  STAGE_W(W_ih, 0) MM(rp, sA1)
  STAGE_W(W_hh, 0) MM(rp, sA2)
  STAGE_W(W_ih, 1) MM(zp, sA1)
  STAGE_W(W_hh, 1) MM(zp, sA2)
  STAGE_W(W_ih, 2) MM(inn, sA1)
  STAGE_W(W_hh, 2) MM(hnn, sA2)
#undef STAGE_W
#undef MM

  #pragma unroll
  for (int nt = 0; nt < 8; ++nt) {
    int col = nt * 16 + l15;
    float bir = b_ih[col], biz = b_ih[col + 128], bin = b_ih[col + 256];
    float bhr = b_hh[col], bhz = b_hh[col + 128], bhn = b_hh[col + 256];
    #pragma unroll
    for (int j = 0; j < 4; ++j) {
      long r = row0 + wv * 16 + kg * 4 + j;
      if (r >= G) continue;
      float pre_r = rp[nt][j] + bir + bhr;
      float pre_z = zp[nt][j] + biz + bhz;
      float rr = 1.f / (1.f + __expf(-pre_r));
      float zz = 1.f / (1.f + __expf(-pre_z));
      float nn = tanhf(inn[nt][j] + bin + rr * (hnn[nt][j] + bhn));
      float hp = cur[r * 128 + col];
      nxt[r * 128 + col] = fmaxf((1.f - zz) * nn + zz * hp, 0.f);
    }
  }
}

extern "C" void kernel_launch(void* const* d_in, const int* in_sizes, int n_in,
                              void* d_out, int out_size, void* d_ws, size_t ws_size,
                              hipStream_t stream) {
  const float* x        = (const float*)d_in[0];
  const int*   batch    = (const int*)d_in[1];
  const float* Wl       = (const float*)d_in[2];
  const float* bl       = (const float*)d_in[3];
  const float* Wr       = (const float*)d_in[4];
  const float* br       = (const float*)d_in[5];
  const float* att      = (const float*)d_in[6];
  const float* gat_bias = (const float*)d_in[7];
  const float* W_ih     = (const float*)d_in[8];
  const float* W_hh     = (const float*)d_in[9];
  const float* b_ih     = (const float*)d_in[10];
  const float* b_hh     = (const float*)d_in[11];
  const float* Wfc      = (const float*)d_in[12];
  const float* bfc      = (const float*)d_in[13];
  const int N = in_sizes[1];
  const int G = out_size / G_DIM;
  float* outf = (float*)d_out;

  char* ws = (char*)d_ws;
  size_t off = 0;
  auto alloc = [&](size_t bytes) -> void* {
    void* p = ws + off;
    off = (off + bytes + 255) & ~(size_t)255;
    return p;
  };
  int*    seg   = (int*)alloc(((size_t)G + 1) * sizeof(int));
  float*  out_a = (float*)alloc((size_t)G * G_DIM * sizeof(float));
  float*  out_b = (float*)alloc((size_t)G * G_DIM * sizeof(float));
  float*  xr    = (float*)alloc((size_t)G * G_DIM * sizeof(float));
  float*  hbuf  = (float*)alloc((size_t)G * G_DIM * sizeof(float));
  __bf16* xl    = (__bf16*)alloc((size_t)N * G_DIM * sizeof(ushort));
  (void)ws_size; (void)n_in;

  const int pool4 = G * G_DIM / 4;

  k_seg<<<(N + 255) / 256, 256, 0, stream>>>(batch, seg, N, G);
  k_zero4<<<(pool4 + 255) / 256, 256, 0, stream>>>((float4*)out_a, pool4);

  const int ntiles_big = (N + 63) / 64;
  k_xlgemm<<<2048, 256, 0, stream>>>(x, Wl, bl, batch, xl, out_a, N, ntiles_big);
  k_relu4<<<(pool4 + 255) / 256, 256, 0, stream>>>((float4*)out_a, pool4);

  const int ntiles_g = (G + 63) / 64;
  const float* cur = out_a;
  float* nxt = out_b;
  for (int t = 0; t < 3; ++t) {
    k_gemm128<<<ntiles_g, 256, 0, stream>>>(cur, Wr, br, xr, G);
    k_gat<<<(G + 3) / 4, 256, 0, stream>>>(xl, xr, seg, att, gat_bias, hbuf, G);
    k_grublock<<<ntiles_g, 256, 0, stream>>>(hbuf, cur, W_ih, W_hh, b_ih, b_hh, nxt, G);
    const float* tmp = cur;
    cur = nxt;
    nxt = (float*)tmp;
  }
  k_gemm128<<<ntiles_g, 256, 0, stream>>>(cur, Wfc, bfc, outf, G);
}